// Round 5
// baseline (24197.673 us; speedup 1.0000x reference)
//
#include <hip/hip_runtime.h>
#include <hip/hip_bf16.h>
#include <math.h>

#define B_  32
#define T_  512
#define D_  1024
#define H_  1024
#define G4_ 4096
#define NB  256
#define NT  512

typedef __attribute__((ext_vector_type(8))) short short8;
typedef __attribute__((ext_vector_type(4))) float f32x4;

__device__ __forceinline__ float hardsig(float z) {
    return fminf(fmaxf(0.2f * z + 0.5f, 0.0f), 1.0f);
}
__device__ __forceinline__ float fast_tanh(float x) {
    float ax = fabsf(x);
    float e  = __expf(-2.0f * ax);          // v_exp_f32-based
    float t  = (1.0f - e) / (1.0f + e);
    return copysignf(t, x);
}
// split fp32 into hi+lo bf16 (RTN)
__device__ __forceinline__ void split2(float f, short& hi, short& lo) {
    __hip_bfloat16 h = __float2bfloat16(f);
    float hf = __bfloat162float(h);
    __hip_bfloat16 l = __float2bfloat16(f - hf);
    hi = *(short*)&h; lo = *(short*)&l;
}
// 16B coherent (L2-bypassing) load of 8 bf16
__device__ __forceinline__ short8 ld16_coh(const unsigned short* p) {
    const unsigned long long* q = (const unsigned long long*)p;
    unsigned long long a = __hip_atomic_load(q + 0, __ATOMIC_RELAXED, __HIP_MEMORY_SCOPE_AGENT);
    unsigned long long b = __hip_atomic_load(q + 1, __ATOMIC_RELAXED, __HIP_MEMORY_SCOPE_AGENT);
    union { unsigned long long u[2]; short8 s; } cv;
    cv.u[0] = a; cv.u[1] = b;
    return cv.s;
}

// MODE 0: correct, globally synchronized. MODE 1: no-sync throughput probe.
template<int MODE>
__global__ __launch_bounds__(NT, 1)
void lstm_p(const float* __restrict__ x,
            const float* __restrict__ W0, const float* __restrict__ U0, const float* __restrict__ b0,
            const float* __restrict__ W1, const float* __restrict__ U1, const float* __restrict__ b1,
            unsigned short* __restrict__ h1hi, unsigned short* __restrict__ h1lo,
            unsigned short* __restrict__ h2hi, unsigned short* __restrict__ h2lo,
            const unsigned short* __restrict__ zp,
            unsigned* __restrict__ bar,   // leaf[i*16] i<16, root@[256], genrep@[320+i*16]
            float* __restrict__ out)
{
    __shared__ short Wh[2][16384];        // 64 KB  hi-bf16 weights (frag order)
    __shared__ short Wl[2][16384];        // 64 KB  lo-bf16 weights
    __shared__ float red[2][2][4][16][17];// 17 KB  partial C tiles [par][mt][s][row][col+pad]

    const unsigned TW = MODE ? 63u : 0xffffffffu;  // probe: 64-step h1 window

    const int tid  = threadIdx.x;
    const int bid  = blockIdx.x;
    const int j0   = bid * 4;            // owned h-columns
    const int w    = tid >> 6;
    const int lane = tid & 63;
    const int s    = w >> 1;             // 0,1: x@W waves; 2,3: h@U waves
    const int mt   = w & 1;              // batch half
    const int ln15 = lane & 15;
    const int lhi  = lane >> 4;
    const int b    = mt * 16 + ln15;     // A-row (batch) this lane loads

    // single-wave combine (wave 0): lane handles outputs idx = lane*2 + {0,1}
    const int ccb  = (lane * 2) >> 2;    // batch row
    const int ccj0 = (lane * 2) & 3;     // first owned-col idx (0 or 2)

    float creg_[2] = {0.f, 0.f};
    float bias_[2][4];

    #pragma unroll
    for (int layer = 0; layer < 2; ++layer) {
        const float* Wmat = layer ? W1 : W0;
        const float* Umat = layer ? U1 : U0;
        const float* bl   = layer ? b1 : b0;

        __syncthreads();  // all waves done with previous layer's LDS
        // ---- convert W,U 16-col slices to split-bf16 fragment layout ----
        for (int m = 0; m < 2; ++m) {
            const float* src = m ? Umat : Wmat;
            for (int fi = tid; fi < 4096; fi += NT) {
                int g = fi & 3, k = fi >> 2;
                float4 v = *(const float4*)&src[(size_t)k * G4_ + (size_t)g * H_ + j0];
                int ki = k >> 5, kf = k & 31;
                int e = kf & 7;
                int flbase = ((kf >> 3) << 4) | (g << 2);
                short hi, lo;
                split2(v.x, hi, lo); Wh[m][ki*512+(flbase+0)*8+e]=hi; Wl[m][ki*512+(flbase+0)*8+e]=lo;
                split2(v.y, hi, lo); Wh[m][ki*512+(flbase+1)*8+e]=hi; Wl[m][ki*512+(flbase+1)*8+e]=lo;
                split2(v.z, hi, lo); Wh[m][ki*512+(flbase+2)*8+e]=hi; Wl[m][ki*512+(flbase+2)*8+e]=lo;
                split2(v.w, hi, lo); Wh[m][ki*512+(flbase+3)*8+e]=hi; Wl[m][ki*512+(flbase+3)*8+e]=lo;
            }
        }
        if (w == 0) {
            #pragma unroll
            for (int o = 0; o < 2; ++o)
                #pragma unroll
                for (int g = 0; g < 4; ++g)
                    bias_[o][g] = bl[(size_t)g * H_ + j0 + ccj0 + o];
            creg_[0] = 0.f; creg_[1] = 0.f;
        }
        __syncthreads();

        for (int t = 0; t < T_; ++t) {
            const int q   = layer * T_ + t;
            const int par = q & 1;
            f32x4 a0 = {0,0,0,0}, a1 = {0,0,0,0}, a2 = {0,0,0,0};

            if (s < 2) {
                // ---------------- x-phase (never waits) ----------------
                if (layer == 0) {
                    const float* xr = x + ((size_t)b * T_ + t) * D_;
                    #pragma unroll 4
                    for (int ki = 0; ki < 16; ++ki) {
                        const int d = s * 512 + ki * 32 + lhi * 8;
                        float4 v0 = *(const float4*)&xr[d];
                        float4 v1 = *(const float4*)&xr[d + 4];
                        short8 ah, al; short hi, lo;
                        split2(v0.x,hi,lo); ah[0]=hi; al[0]=lo;
                        split2(v0.y,hi,lo); ah[1]=hi; al[1]=lo;
                        split2(v0.z,hi,lo); ah[2]=hi; al[2]=lo;
                        split2(v0.w,hi,lo); ah[3]=hi; al[3]=lo;
                        split2(v1.x,hi,lo); ah[4]=hi; al[4]=lo;
                        split2(v1.y,hi,lo); ah[5]=hi; al[5]=lo;
                        split2(v1.z,hi,lo); ah[6]=hi; al[6]=lo;
                        split2(v1.w,hi,lo); ah[7]=hi; al[7]=lo;
                        const int kiG = s * 16 + ki;
                        short8 wh = *(const short8*)&Wh[0][kiG*512 + lane*8];
                        short8 wl = *(const short8*)&Wl[0][kiG*512 + lane*8];
                        a0 = __builtin_amdgcn_mfma_f32_16x16x32_bf16(ah, wh, a0, 0, 0, 0);
                        a1 = __builtin_amdgcn_mfma_f32_16x16x32_bf16(al, wh, a1, 0, 0, 0);
                        a2 = __builtin_amdgcn_mfma_f32_16x16x32_bf16(ah, wl, a2, 0, 0, 0);
                    }
                } else {
                    const unsigned short* xh = h1hi + ((size_t)(t & TW) * B_ + b) * H_;
                    const unsigned short* xl = h1lo + ((size_t)(t & TW) * B_ + b) * H_;
                    #pragma unroll 4
                    for (int ki = 0; ki < 16; ++ki) {
                        const int d = s * 512 + ki * 32 + lhi * 8;
                        short8 ah = *(const short8*)&xh[d];
                        short8 al = *(const short8*)&xl[d];
                        const int kiG = s * 16 + ki;
                        short8 wh = *(const short8*)&Wh[0][kiG*512 + lane*8];
                        short8 wl = *(const short8*)&Wl[0][kiG*512 + lane*8];
                        a0 = __builtin_amdgcn_mfma_f32_16x16x32_bf16(ah, wh, a0, 0, 0, 0);
                        a1 = __builtin_amdgcn_mfma_f32_16x16x32_bf16(al, wh, a1, 0, 0, 0);
                        a2 = __builtin_amdgcn_mfma_f32_16x16x32_bf16(ah, wl, a2, 0, 0, 0);
                    }
                }
            } else {
                // ---------------- h-phase: wait for step q-1 globally done ----------------
                if constexpr (MODE == 0) {
                    if (t > 0) {
                        if (lane == 0) {
                            const unsigned* gp = &bar[320 + (bid & 15) * 16];
                            while (__hip_atomic_load(gp, __ATOMIC_RELAXED, __HIP_MEMORY_SCOPE_AGENT) < (unsigned)q)
                                __builtin_amdgcn_s_sleep(1);
                        }
                        asm volatile("" ::: "memory");   // no data-load hoisting above the poll
                    }
                }
                const int sk = (s - 2) * 512;
                if (layer == 0) {
                    const unsigned short* hh = (t == 0) ? (zp + (size_t)b * H_)
                                                        : (h1hi + ((size_t)((t-1) & TW) * B_ + b) * H_);
                    const unsigned short* hl = (t == 0) ? (zp + (size_t)b * H_)
                                                        : (h1lo + ((size_t)((t-1) & TW) * B_ + b) * H_);
                    #pragma unroll 4
                    for (int ki = 0; ki < 16; ++ki) {
                        const int d = sk + ki * 32 + lhi * 8;
                        short8 ah, al;
                        if constexpr (MODE == 0) {          // plain: first touch post-publish -> valid
                            ah = *(const short8*)&hh[d];
                            al = *(const short8*)&hl[d];
                        } else {                            // probe: force LLC like A's miss path
                            ah = ld16_coh(&hh[d]);
                            al = ld16_coh(&hl[d]);
                        }
                        const int kiG = (s - 2) * 16 + ki;
                        short8 uh = *(const short8*)&Wh[1][kiG*512 + lane*8];
                        short8 ul = *(const short8*)&Wl[1][kiG*512 + lane*8];
                        a0 = __builtin_amdgcn_mfma_f32_16x16x32_bf16(ah, uh, a0, 0, 0, 0);
                        a1 = __builtin_amdgcn_mfma_f32_16x16x32_bf16(al, uh, a1, 0, 0, 0);
                        a2 = __builtin_amdgcn_mfma_f32_16x16x32_bf16(ah, ul, a2, 0, 0, 0);
                    }
                } else {
                    // h2 double-buffer reuses addresses -> bypass caches
                    const unsigned short* hh = (t == 0) ? (zp + (size_t)b * H_)
                                                        : (h2hi + (size_t)((t-1)&1) * B_ * H_ + (size_t)b * H_);
                    const unsigned short* hl = (t == 0) ? (zp + (size_t)b * H_)
                                                        : (h2lo + (size_t)((t-1)&1) * B_ * H_ + (size_t)b * H_);
                    #pragma unroll 4
                    for (int ki = 0; ki < 16; ++ki) {
                        const int d = sk + ki * 32 + lhi * 8;
                        short8 ah = ld16_coh(&hh[d]);
                        short8 al = ld16_coh(&hl[d]);
                        const int kiG = (s - 2) * 16 + ki;
                        short8 uh = *(const short8*)&Wh[1][kiG*512 + lane*8];
                        short8 ul = *(const short8*)&Wl[1][kiG*512 + lane*8];
                        a0 = __builtin_amdgcn_mfma_f32_16x16x32_bf16(ah, uh, a0, 0, 0, 0);
                        a1 = __builtin_amdgcn_mfma_f32_16x16x32_bf16(al, uh, a1, 0, 0, 0);
                        a2 = __builtin_amdgcn_mfma_f32_16x16x32_bf16(ah, ul, a2, 0, 0, 0);
                    }
                }
            }

            f32x4 acc = a0 + a1 + a2;
            #pragma unroll
            for (int i = 0; i < 4; ++i)
                red[par][mt][s][lhi*4+i][ln15] = acc[i];
            __syncthreads();   // the only per-step intra-block barrier

            // ---- combine + state update + publish + arrive (wave 0 only) ----
            if (w == 0) {
                float hv[2]; short his[2], los[2];
                #pragma unroll
                for (int o = 0; o < 2; ++o) {
                    const int idx = lane * 2 + o;
                    const int cb  = idx >> 2, cj = idx & 3;
                    const int rmt = cb >> 4, rr = cb & 15;
                    float z[4];
                    #pragma unroll
                    for (int g = 0; g < 4; ++g) {
                        const int n = g * 4 + cj;
                        z[g] = red[par][rmt][0][rr][n] + red[par][rmt][1][rr][n]
                             + red[par][rmt][2][rr][n] + red[par][rmt][3][rr][n] + bias_[o][g];
                    }
                    float ig = hardsig(z[0]);
                    float fg = hardsig(z[1]);
                    float gg = fast_tanh(z[2]);
                    float og = hardsig(z[3]);
                    creg_[o] = fg * creg_[o] + ig * gg;
                    hv[o] = og * fast_tanh(creg_[o]);
                    split2(hv[o], his[o], los[o]);
                }
                unsigned vhi = (unsigned)(unsigned short)his[0] | ((unsigned)(unsigned short)his[1] << 16);
                unsigned vlo = (unsigned)(unsigned short)los[0] | ((unsigned)(unsigned short)los[1] << 16);
                const size_t base = (size_t)ccb * H_ + j0 + ccj0;
                unsigned short *ahi, *alo; size_t off;
                if (layer == 0) { ahi = h1hi; alo = h1lo; off = (size_t)(t & TW) * B_ * H_ + base; }
                else            { ahi = h2hi; alo = h2lo; off = (size_t)(t & 1) * B_ * H_ + base; }
                __hip_atomic_store((unsigned*)&ahi[off], vhi, __ATOMIC_RELAXED, __HIP_MEMORY_SCOPE_AGENT);
                __hip_atomic_store((unsigned*)&alo[off], vlo, __ATOMIC_RELAXED, __HIP_MEMORY_SCOPE_AGENT);
                if (layer == 1 && t == T_ - 1) *(float2*)&out[base] = make_float2(hv[0], hv[1]);

                if constexpr (MODE == 0) {
                    // all lanes' publishes ACKed at LLC before arriving
                    asm volatile("s_waitcnt vmcnt(0)" ::: "memory");
                    if (lane == 0) {
                        unsigned old = __hip_atomic_fetch_add(&bar[(bid >> 4) * 16], 1u,
                                                              __ATOMIC_RELAXED, __HIP_MEMORY_SCOPE_AGENT);
                        if ((old & 15u) == 15u) {        // 16 blocks/leaf, 1 arrival/block/step
                            unsigned r = __hip_atomic_fetch_add(&bar[256], 1u,
                                                                __ATOMIC_RELAXED, __HIP_MEMORY_SCOPE_AGENT);
                            if ((r & 15u) == 15u) {      // 16 leaf-closers/step
                                #pragma unroll
                                for (int i = 0; i < 16; ++i)
                                    __hip_atomic_store(&bar[320 + i * 16], (unsigned)(q + 1),
                                                       __ATOMIC_RELAXED, __HIP_MEMORY_SCOPE_AGENT);
                            }
                        }
                    }
                }
            }
        }
    }
}

extern "C" void kernel_launch(void* const* d_in, const int* in_sizes, int n_in,
                              void* d_out, int out_size, void* d_ws, size_t ws_size,
                              hipStream_t stream) {
    const float* x  = (const float*)d_in[0];
    const float* W0 = (const float*)d_in[1];
    const float* U0 = (const float*)d_in[2];
    const float* b0 = (const float*)d_in[3];
    const float* W1 = (const float*)d_in[4];
    const float* U1 = (const float*)d_in[5];
    const float* b1 = (const float*)d_in[6];
    float* out = (float*)d_out;

    char* ws = (char*)d_ws;
    const size_t off_h1hi = 0;          // 32 MiB [T][B][H]
    const size_t off_h1lo = 33554432;   // 32 MiB
    const size_t off_h2hi = 67108864;   // 128 KiB [2][B][H]
    const size_t off_h2lo = 67239936;   // 128 KiB
    const size_t off_zp   = 67371008;   // 128 KiB zeros
    const size_t off_bar  = 67502080;   //   4 KiB barrier state
    // no-sync probe scratch (never read by validation)
    const size_t off_p1hi = 67506176;   //  4 MiB [64][B][H]
    const size_t off_p1lo = 71700480;   //  4 MiB
    const size_t off_p2hi = 75894784;   // 128 KiB
    const size_t off_p2lo = 76025856;   // 128 KiB
    const size_t off_pout = 76156928;   // 128 KiB

    unsigned short* h1hi = (unsigned short*)(ws + off_h1hi);
    unsigned short* h1lo = (unsigned short*)(ws + off_h1lo);
    unsigned short* h2hi = (unsigned short*)(ws + off_h2hi);
    unsigned short* h2lo = (unsigned short*)(ws + off_h2lo);
    unsigned short* zp   = (unsigned short*)(ws + off_zp);
    unsigned* bar        = (unsigned*)(ws + off_bar);
    unsigned short* p1hi = (unsigned short*)(ws + off_p1hi);
    unsigned short* p1lo = (unsigned short*)(ws + off_p1lo);
    unsigned short* p2hi = (unsigned short*)(ws + off_p2hi);
    unsigned short* p2lo = (unsigned short*)(ws + off_p2lo);
    float* pout          = (float*)(ws + off_pout);

    // reset zero page + barrier counters every launch (graph-capture safe)
    hipMemsetAsync(ws + off_zp, 0, 131072 + 4096, stream);

    // Dispatch A: correct, validated result
    hipLaunchKernelGGL((lstm_p<0>), dim3(NB), dim3(NT), 0, stream,
                       x, W0, U0, b0, W1, U1, b1,
                       h1hi, h1lo, h2hi, h2lo, zp, bar, out);
    // Dispatch B: no-sync throughput probe (diagnostic; writes scratch only)
    hipLaunchKernelGGL((lstm_p<1>), dim3(NB), dim3(NT), 0, stream,
                       x, W0, U0, b0, W1, U1, b1,
                       p1hi, p1lo, p2hi, p2lo, zp, bar, pout);
}

// Round 6
// 6279.767 us; speedup vs baseline: 3.8533x; 3.8533x over previous
//
#include <hip/hip_runtime.h>
#include <hip/hip_bf16.h>
#include <math.h>

#define B_  32
#define T_  512
#define D_  1024
#define H_  1024
#define G4_ 4096
#define NBLK 256
#define NT  512

typedef __attribute__((ext_vector_type(8))) _Float16 f16x8;
typedef __attribute__((ext_vector_type(4))) float   f32x4;

__device__ __forceinline__ float hardsig(float z) {
    return fminf(fmaxf(0.2f * z + 0.5f, 0.0f), 1.0f);
}
__device__ __forceinline__ float fast_tanh(float x) {
    float ax = fabsf(x);
    float e  = __expf(-2.0f * ax);
    float t  = (1.0f - e) / (1.0f + e);
    return copysignf(t, x);
}
// wave-level wait until *p >= tgt (lane0 polls, whole wave blocked by exec)
__device__ __forceinline__ void wait_ge(const unsigned* p, unsigned tgt) {
    if ((threadIdx.x & 63) == 0) {
        while (__hip_atomic_load(p, __ATOMIC_RELAXED, __HIP_MEMORY_SCOPE_AGENT) < tgt)
            __builtin_amdgcn_s_sleep(2);
    }
    asm volatile("" ::: "memory");   // no data-load hoisting above the poll
}
// 16B L2-bypassing load of 8 fp16 (for address-reused ring buffers)
__device__ __forceinline__ f16x8 ld16c(const _Float16* p) {
    const unsigned long long* q = (const unsigned long long*)p;
    unsigned long long a = __hip_atomic_load(q + 0, __ATOMIC_RELAXED, __HIP_MEMORY_SCOPE_AGENT);
    unsigned long long b = __hip_atomic_load(q + 1, __ATOMIC_RELAXED, __HIP_MEMORY_SCOPE_AGENT);
    union { unsigned long long u[2]; f16x8 h; } cv;
    cv.u[0] = a; cv.u[1] = b;
    return cv.h;
}

// Dual-domain pipelined 2-layer LSTM.
// blocks 0..127  : layer 0 (x@W0 + h1@U0), publishes h1seq[t], advances gen0
// blocks 128..255: layer 1 (h1[t]@W1 + h2@U1), trails gen0 by 1 step, advances gen1
__global__ __launch_bounds__(NT, 1)
void lstm_pipe(const float* __restrict__ x,
               const float* __restrict__ W0, const float* __restrict__ U0, const float* __restrict__ b0,
               const float* __restrict__ W1, const float* __restrict__ U1, const float* __restrict__ b1,
               _Float16* __restrict__ h1seq,   // [T][B][H] fp16
               _Float16* __restrict__ h2ring,  // [2][B][H] fp16
               const _Float16* __restrict__ zp,// [B][H] fp16 zeros
               unsigned* __restrict__ bar,     // per-domain 4KB: leaf[i*16] i<16, root@[256], gen@[320+i*16]
               float* __restrict__ out)        // [B][H] fp32
{
    __shared__ _Float16 Bfrag[2][2][32][64][8]; // 128 KiB [mat][ntile][kiG][lane][e]
    __shared__ float red[2][2][2][2][16][17];   //  17 KiB [par][mt][nt][role][row][col+pad]

    const int tid  = threadIdx.x;
    const int bid  = blockIdx.x;
    const int dom  = bid >> 7;          // 0 = layer0, 1 = layer1
    const int dbid = bid & 127;
    const int j0   = dbid * 8;          // owned h-columns j0..j0+7
    const int w    = tid >> 6, lane = tid & 63;
    const int mt   = w & 1;             // batch half (m-tile)
    const int nt   = (w >> 1) & 1;      // n-tile (16 of 32 gate-cols)
    const int role = w >> 2;            // 0 = x-side (W-matmul), 1 = h-side (U-matmul)
    const int arow = mt * 16 + (lane & 15);
    const int koff = (lane >> 4) * 8;

    unsigned* mybar = bar + dom * 1024;
    unsigned* leafp = &mybar[(dbid >> 3) * 16];
    unsigned* rootp = &mybar[256];
    const unsigned* genown = &mybar[320 + (dbid >> 3) * 16];
    const unsigned* gen0   = &bar[320 + (dbid >> 3) * 16];   // dom0 replicas

    const float* Wmat = dom ? W1 : W0;
    const float* Umat = dom ? U1 : U0;
    const float* bl   = dom ? b1 : b0;

    // ---- prologue: convert this block's W,U 8-col slices to fp16 fragment layout ----
    for (int fi = tid; fi < 8192; fi += NT) {          // (m, k, g)
        const int m = fi >> 12, k = (fi >> 2) & 1023, g = fi & 3;
        const float* src = (m ? Umat : Wmat) + (size_t)k * G4_ + (size_t)g * H_ + j0;
        float4 v0 = *(const float4*)&src[0];
        float4 v1 = *(const float4*)&src[4];
        const int kiG = k >> 5, lrow = (k >> 3) & 3, e = k & 7;
        _Float16* dst = &Bfrag[m][g >> 1][kiG][lrow * 16 + (g & 1) * 8][e];
        dst[0*8] = (_Float16)v0.x; dst[1*8] = (_Float16)v0.y;
        dst[2*8] = (_Float16)v0.z; dst[3*8] = (_Float16)v0.w;
        dst[4*8] = (_Float16)v1.x; dst[5*8] = (_Float16)v1.y;
        dst[6*8] = (_Float16)v1.z; dst[7*8] = (_Float16)v1.w;
    }

    float creg = 0.f, bias_[4] = {0.f, 0.f, 0.f, 0.f};
    if (role == 0) {
        const int idx = w * 64 + lane, cj = idx & 7;
        #pragma unroll
        for (int g = 0; g < 4; ++g) bias_[g] = bl[(size_t)g * H_ + j0 + cj];
    }
    __syncthreads();

    for (int t = 0; t < T_; ++t) {
        const int par = t & 1;
        f32x4 acc = {0.f, 0.f, 0.f, 0.f};

        if (role == 0) {
            // ---------------- x-side ----------------
            if (dom == 0) {
                // layer0: A = x (fp32 -> fp16 on the fly). Never waits.
                const float* xr = x + ((size_t)arow * T_ + t) * D_;
                #pragma unroll 8
                for (int kiG = 0; kiG < 32; ++kiG) {
                    const int k = kiG * 32 + koff;
                    float4 v0 = *(const float4*)&xr[k];
                    float4 v1 = *(const float4*)&xr[k + 4];
                    f16x8 af;
                    af[0]=(_Float16)v0.x; af[1]=(_Float16)v0.y; af[2]=(_Float16)v0.z; af[3]=(_Float16)v0.w;
                    af[4]=(_Float16)v1.x; af[5]=(_Float16)v1.y; af[6]=(_Float16)v1.z; af[7]=(_Float16)v1.w;
                    f16x8 bf = *(const f16x8*)&Bfrag[0][nt][kiG][lane][0];
                    acc = __builtin_amdgcn_mfma_f32_16x16x32_f16(af, bf, acc, 0, 0, 0);
                }
            } else {
                // layer1: A = h1[t], gated by layer0's gen
                wait_ge(gen0, (unsigned)(t + 1));
                const _Float16* hp = h1seq + ((size_t)t * B_ + arow) * H_;
                #pragma unroll 8
                for (int kiG = 0; kiG < 32; ++kiG) {
                    f16x8 af = *(const f16x8*)&hp[kiG * 32 + koff];
                    f16x8 bf = *(const f16x8*)&Bfrag[0][nt][kiG][lane][0];
                    acc = __builtin_amdgcn_mfma_f32_16x16x32_f16(af, bf, acc, 0, 0, 0);
                }
            }
        } else {
            // ---------------- h-side (own-layer recurrence) ----------------
            if (t > 0) wait_ge(genown, (unsigned)t);
            if (dom == 0) {
                const _Float16* hp = (t == 0) ? (zp + (size_t)arow * H_)
                                              : (h1seq + ((size_t)(t - 1) * B_ + arow) * H_);
                #pragma unroll 8
                for (int kiG = 0; kiG < 32; ++kiG) {
                    f16x8 af = *(const f16x8*)&hp[kiG * 32 + koff];
                    f16x8 bf = *(const f16x8*)&Bfrag[1][nt][kiG][lane][0];
                    acc = __builtin_amdgcn_mfma_f32_16x16x32_f16(af, bf, acc, 0, 0, 0);
                }
            } else {
                // h2 ring reuses addresses -> L2-bypassing loads
                const _Float16* hp = (t == 0) ? (zp + (size_t)arow * H_)
                                              : (h2ring + (size_t)((t - 1) & 1) * B_ * H_ + (size_t)arow * H_);
                if (t == 0) {
                    #pragma unroll 8
                    for (int kiG = 0; kiG < 32; ++kiG) {
                        f16x8 af = *(const f16x8*)&hp[kiG * 32 + koff];
                        f16x8 bf = *(const f16x8*)&Bfrag[1][nt][kiG][lane][0];
                        acc = __builtin_amdgcn_mfma_f32_16x16x32_f16(af, bf, acc, 0, 0, 0);
                    }
                } else {
                    #pragma unroll 8
                    for (int kiG = 0; kiG < 32; ++kiG) {
                        f16x8 af = ld16c(&hp[kiG * 32 + koff]);
                        f16x8 bf = *(const f16x8*)&Bfrag[1][nt][kiG][lane][0];
                        acc = __builtin_amdgcn_mfma_f32_16x16x32_f16(af, bf, acc, 0, 0, 0);
                    }
                }
            }
        }

        #pragma unroll
        for (int i = 0; i < 4; ++i)
            red[par][mt][nt][role][(lane >> 4) * 4 + i][lane & 15] = acc[i];
        __syncthreads();   // the only per-step intra-block barrier

        // ---- combine + state update + coherent publish + arrive (waves 0..3) ----
        if (role == 0) {
            const int idx = w * 64 + lane, cb = idx >> 3, cj = idx & 7;
            const int rmt = cb >> 4, rr = cb & 15;
            float z[4];
            #pragma unroll
            for (int g = 0; g < 4; ++g) {
                const int nc = (g & 1) * 8 + cj;
                z[g] = red[par][rmt][g >> 1][0][rr][nc]
                     + red[par][rmt][g >> 1][1][rr][nc] + bias_[g];
            }
            float ig = hardsig(z[0]), fg = hardsig(z[1]);
            float gg = fast_tanh(z[2]), og = hardsig(z[3]);
            creg = fg * creg + ig * gg;
            float hval = og * fast_tanh(creg);
            _Float16 hf = (_Float16)hval;
            unsigned short us; __builtin_memcpy(&us, &hf, 2);
            unsigned up = (unsigned)us;
            unsigned op = (unsigned)__shfl_xor((int)up, 1);
            if (!(lane & 1)) {   // even lane stores dword covering (cj, cj+1)
                unsigned val = up | (op << 16);
                const size_t soff = (size_t)cb * H_ + j0 + cj;
                unsigned* dst = (dom == 0)
                    ? (unsigned*)&h1seq[(size_t)t * B_ * H_ + soff]
                    : (unsigned*)&h2ring[(size_t)(t & 1) * B_ * H_ + soff];
                __hip_atomic_store(dst, val, __ATOMIC_RELAXED, __HIP_MEMORY_SCOPE_AGENT);
            }
            if (dom == 1 && t == T_ - 1) out[(size_t)cb * H_ + j0 + cj] = hval;
            // all lanes' publishes ACKed at LLC before arriving
            asm volatile("s_waitcnt vmcnt(0)" ::: "memory");
            if (lane == 0) {
                unsigned old = __hip_atomic_fetch_add(leafp, 1u, __ATOMIC_RELAXED, __HIP_MEMORY_SCOPE_AGENT);
                if ((old & 31u) == 31u) {       // 8 blocks x 4 waves per leaf
                    unsigned r = __hip_atomic_fetch_add(rootp, 1u, __ATOMIC_RELAXED, __HIP_MEMORY_SCOPE_AGENT);
                    if ((r & 15u) == 15u) {     // 16 leaf-closers per step
                        #pragma unroll
                        for (int i = 0; i < 16; ++i)
                            __hip_atomic_store(&mybar[320 + i * 16], (unsigned)(t + 1),
                                               __ATOMIC_RELAXED, __HIP_MEMORY_SCOPE_AGENT);
                    }
                }
            }
        }
    }
}

extern "C" void kernel_launch(void* const* d_in, const int* in_sizes, int n_in,
                              void* d_out, int out_size, void* d_ws, size_t ws_size,
                              hipStream_t stream) {
    const float* x  = (const float*)d_in[0];
    const float* W0 = (const float*)d_in[1];
    const float* U0 = (const float*)d_in[2];
    const float* b0 = (const float*)d_in[3];
    const float* W1 = (const float*)d_in[4];
    const float* U1 = (const float*)d_in[5];
    const float* b1 = (const float*)d_in[6];
    float* out = (float*)d_out;

    char* ws = (char*)d_ws;
    const size_t off_h1 = 0;          // 32 MiB  h1seq fp16 [T][B][H]
    const size_t off_h2 = 33554432;   // 128 KiB h2 ring fp16 [2][B][H]
    const size_t off_zp = 33685504;   //  64 KiB fp16 zeros [B][H]
    const size_t off_br = 33751040;   //   8 KiB barrier state (2 domains x 4 KiB)

    _Float16* h1seq = (_Float16*)(ws + off_h1);
    _Float16* h2ring= (_Float16*)(ws + off_h2);
    _Float16* zp    = (_Float16*)(ws + off_zp);
    unsigned* bar   = (unsigned*)(ws + off_br);

    // reset zero page + barrier counters every launch (graph-capture safe)
    hipMemsetAsync(ws + off_zp, 0, 65536 + 8192, stream);

    hipLaunchKernelGGL(lstm_pipe, dim3(NBLK), dim3(NT), 0, stream,
                       x, W0, U0, b0, W1, U1, b1,
                       h1seq, h2ring, zp, bar, out);
}

// Round 7
// 3940.126 us; speedup vs baseline: 6.1413x; 1.5938x over previous
//
#include <hip/hip_runtime.h>
#include <math.h>

#define B_  32
#define T_  512
#define H_  1024
#define G4_ 4096
#define NT  512

typedef __attribute__((ext_vector_type(8))) _Float16 f16x8;
typedef __attribute__((ext_vector_type(4))) float   f32x4;

#define ROWP 1032   // padded LDS row (fp16 units) for 1024-row staging
#define WROW 264    // padded LDS row for weight-stage chunks (256 k + 8)

__device__ __forceinline__ float hardsig(float z) {
    return fminf(fmaxf(0.2f * z + 0.5f, 0.0f), 1.0f);
}
__device__ __forceinline__ float fast_tanh(float x) {
    float ax = fabsf(x);
    float e  = __expf(-2.0f * ax);
    float t  = (1.0f - e) / (1.0f + e);
    return copysignf(t, x);
}
__device__ __forceinline__ unsigned ldA(const unsigned* p) {
    return __hip_atomic_load(p, __ATOMIC_RELAXED, __HIP_MEMORY_SCOPE_AGENT);
}
__device__ __forceinline__ void stA32(unsigned* p, unsigned v) {
    __hip_atomic_store(p, v, __ATOMIC_RELAXED, __HIP_MEMORY_SCOPE_AGENT);
}

// Stage a [1024 k] x [64 col] fp32 weight slice (cols = g*1024 + colbase + 0..15 per gate g)
// transposed+fp16 into LDS chunks, and read per-wave MFMA B-fragments into VGPRs.
__device__ __forceinline__ void load_wfrags(const float* M, int colbase, int myrow,
                                            int koff, bool keep, f16x8* wf, _Float16* st) {
    for (int kc = 0; kc < 4; ++kc) {
        __syncthreads();
        #pragma unroll
        for (int it = 0; it < 4; ++it) {
            int id  = it * NT + (int)threadIdx.x;   // 0..2047
            int kl  = id >> 3, gc8 = id & 7;
            int gcol = (gc8 >> 1) * 1024 + colbase + (gc8 & 1) * 8;
            const float* src = M + (size_t)(kc * 256 + kl) * G4_ + gcol;
            float4 v0 = *(const float4*)src;
            float4 v1 = *(const float4*)(src + 4);
            int rb = gc8 * 8;
            st[(rb+0)*WROW+kl]=(_Float16)v0.x; st[(rb+1)*WROW+kl]=(_Float16)v0.y;
            st[(rb+2)*WROW+kl]=(_Float16)v0.z; st[(rb+3)*WROW+kl]=(_Float16)v0.w;
            st[(rb+4)*WROW+kl]=(_Float16)v1.x; st[(rb+5)*WROW+kl]=(_Float16)v1.y;
            st[(rb+6)*WROW+kl]=(_Float16)v1.z; st[(rb+7)*WROW+kl]=(_Float16)v1.w;
        }
        __syncthreads();
        if (keep) {
            #pragma unroll
            for (int kj = 0; kj < 8; ++kj)
                wf[kc*8+kj] = *(const f16x8*)&st[myrow * WROW + kj * 32 + koff];
        }
    }
    __syncthreads();
}

// 3-domain persistent kernel:
//  bid   0- 63 : layer-0 recurrence (16 h-cols each), U0 frags in VGPRs
//  bid  64-127 : layer-1 recurrence (16 h-cols each), W1+U1 frags in VGPRs
//  bid 128-255 : xz engine: xz[t] = x_t @ W0 in 8-step chunks, 4-chunk ring
__global__ __launch_bounds__(NT, 1)
void lstm3(const float* __restrict__ x,
           const float* __restrict__ W0, const float* __restrict__ U0, const float* __restrict__ b0,
           const float* __restrict__ W1, const float* __restrict__ U1, const float* __restrict__ b1,
           _Float16* __restrict__ h1,      // [T][B][H] fp16
           _Float16* __restrict__ h2,      // [T][B][H] fp16
           _Float16* __restrict__ xzr,     // [4][8][B][4H] fp16 ring
           const _Float16* __restrict__ zp,// [B][H] fp16 zeros
           unsigned* __restrict__ ctr,     // ctr[0]:d0 arr, [16]:d1 arr, [32]:eng arr,
                                           // gen0@[64+i*16], gen1@[320+i*16], xzgen@[576+i*16]
           float* __restrict__ out)        // [B][H] fp32
{
    __shared__ __align__(16) char smem[149504];
    _Float16* stA  = (_Float16*)smem;                 // 66048 B  [32][ROWP]
    _Float16* stB  = (_Float16*)(smem + 66048);       // 66048 B  [32][ROWP]
    float*    red0 = (float*)(smem + 66048);          //  8704 B  dom0 [2mt][4g][16][17]
    float*    red1 = (float*)(smem + 132096);         // 17408 B  dom1 [2rl][2mt][4g][16][17]

    const int tid  = threadIdx.x;
    const int bid  = blockIdx.x;
    const int w    = tid >> 6, l = tid & 63;
    const int koff = (l >> 4) * 8;

    // ============================ xz ENGINE ============================
    if (bid >= 128) {
        const int e = bid - 128;            // owns gate-cols [e*32, e*32+32)
        const int gbase = e * 32;
        _Float16* w0l = (_Float16*)smem;    // [32][ROWP] transposed W0 slice, permanent

        #pragma unroll 2
        for (int it = 0; it < 8; ++it) {
            int id = it * NT + tid;         // 0..4095
            int k = id >> 2, gc8 = id & 3;
            const float* src = W0 + (size_t)k * G4_ + gbase + gc8 * 8;
            float4 v0 = *(const float4*)src;
            float4 v1 = *(const float4*)(src + 4);
            int rb = gc8 * 8;
            w0l[(rb+0)*ROWP+k]=(_Float16)v0.x; w0l[(rb+1)*ROWP+k]=(_Float16)v0.y;
            w0l[(rb+2)*ROWP+k]=(_Float16)v0.z; w0l[(rb+3)*ROWP+k]=(_Float16)v0.w;
            w0l[(rb+4)*ROWP+k]=(_Float16)v1.x; w0l[(rb+5)*ROWP+k]=(_Float16)v1.y;
            w0l[(rb+6)*ROWP+k]=(_Float16)v1.z; w0l[(rb+7)*ROWP+k]=(_Float16)v1.w;
        }
        __syncthreads();

        for (int c = 0; c < 64; ++c) {
            if (c >= 4 && tid == 0) {       // ring-slot reuse guard
                const unsigned need = (unsigned)(8 * c - 24);
                while (ldA(&ctr[64 + (e & 15) * 16]) < need) __builtin_amdgcn_s_sleep(1);
            }
            __syncthreads();

            f32x4 acc[2][2] = {{{0,0,0,0},{0,0,0,0}},{{0,0,0,0},{0,0,0,0}}};
            const float* xrow[2];
            #pragma unroll
            for (int p = 0; p < 2; ++p) {
                const int m  = (w * 2 + p) * 16 + (l & 15);
                const int tl = m >> 5, bb = m & 31;
                xrow[p] = x + ((size_t)bb * T_ + (8 * c + tl)) * 1024;
            }
            #pragma unroll 4
            for (int kiG = 0; kiG < 32; ++kiG) {
                const int kk = kiG * 32 + koff;
                f16x8 bf0 = *(const f16x8*)&w0l[( 0 + (l & 15)) * ROWP + kk];
                f16x8 bf1 = *(const f16x8*)&w0l[(16 + (l & 15)) * ROWP + kk];
                #pragma unroll
                for (int p = 0; p < 2; ++p) {
                    float4 v0 = *(const float4*)&xrow[p][kk];
                    float4 v1 = *(const float4*)&xrow[p][kk + 4];
                    f16x8 af;
                    af[0]=(_Float16)v0.x; af[1]=(_Float16)v0.y; af[2]=(_Float16)v0.z; af[3]=(_Float16)v0.w;
                    af[4]=(_Float16)v1.x; af[5]=(_Float16)v1.y; af[6]=(_Float16)v1.z; af[7]=(_Float16)v1.w;
                    acc[p][0] = __builtin_amdgcn_mfma_f32_16x16x32_f16(af, bf0, acc[p][0], 0, 0, 0);
                    acc[p][1] = __builtin_amdgcn_mfma_f32_16x16x32_f16(af, bf1, acc[p][1], 0, 0, 0);
                }
            }
            // write xz chunk (paired fp16 dwords, agent-scope)
            #pragma unroll
            for (int p = 0; p < 2; ++p)
                #pragma unroll
                for (int n = 0; n < 2; ++n)
                    #pragma unroll
                    for (int i = 0; i < 4; ++i) {
                        _Float16 hf = (_Float16)acc[p][n][i];
                        unsigned short us; __builtin_memcpy(&us, &hf, 2);
                        unsigned up = us;
                        unsigned op = (unsigned)__shfl_xor((int)up, 1);
                        if (!(l & 1)) {
                            const int m  = (w * 2 + p) * 16 + (l >> 4) * 4 + i;
                            const int tl = m >> 5, bb = m & 31;
                            size_t off = (((size_t)(c & 3) * 8 + tl) * B_ + bb) * G4_
                                       + gbase + n * 16 + (l & 15);
                            stA32((unsigned*)&xzr[off], up | (op << 16));
                        }
                    }
            asm volatile("s_waitcnt vmcnt(0)" ::: "memory");
            __syncthreads();
            if (tid == 0) {
                unsigned old = __hip_atomic_fetch_add(&ctr[32], 1u, __ATOMIC_RELAXED, __HIP_MEMORY_SCOPE_AGENT);
                if ((old & 127u) == 127u) {
                    #pragma unroll
                    for (int i = 0; i < 16; ++i) stA32(&ctr[576 + i * 16], (unsigned)(c + 1));
                }
            }
        }
        return;
    }

    // ============================ RECURRENCE DOMAINS ============================
    const int dom  = (bid >= 64);
    const int dbid = bid & 63;
    const int jb   = dbid * 16;            // owned h-col base

    // combine mapping: one output per thread
    const int bb   = tid >> 4;             // batch row 0..31
    const int jj   = tid & 15;             // owned col 0..15
    const int jcol = jb + jj;

    float bias_[4];
    {
        const float* bl = dom ? b1 : b0;
        #pragma unroll
        for (int g = 0; g < 4; ++g) bias_[g] = bl[(size_t)g * H_ + jcol];
    }
    float creg = 0.f;

    // weight fragments in VGPRs
    f16x8 wf[32];
    if (dom == 0) {
        const int g = w & 3;
        load_wfrags(U0, jb, g * 16 + (l & 15), koff, true, wf, stA);
    } else {
        const int g = w & 3;
        load_wfrags(W1, jb, g * 16 + (l & 15), koff, (w < 4),  wf, stA);  // x-role waves
        load_wfrags(U1, jb, g * 16 + (l & 15), koff, (w >= 4), wf, stA);  // h-role waves
    }

    for (int t = 0; t < T_; ++t) {
        // ---- wait for producers ----
        if (tid == 0) {
            if (dom == 0) {
                const unsigned xt = (unsigned)((t >> 3) + 1);
                while (ldA(&ctr[576 + (dbid & 15) * 16]) < xt) __builtin_amdgcn_s_sleep(1);
                if (t > 0)
                    while (ldA(&ctr[64 + (dbid & 15) * 16]) < (unsigned)t) __builtin_amdgcn_s_sleep(1);
            } else {
                while (ldA(&ctr[64 + (dbid & 15) * 16]) < (unsigned)(t + 1)) __builtin_amdgcn_s_sleep(1);
                if (t > 0)
                    while (ldA(&ctr[320 + (dbid & 15) * 16]) < (unsigned)t) __builtin_amdgcn_s_sleep(1);
            }
        }
        __syncthreads();   // S1: release

        // ---- stage A-operand(s) into LDS (padded rows) ----
        {
            const int r = tid >> 4, ch = tid & 15;
            if (dom == 0) {
                const _Float16* s1 = (t ? h1 + ((size_t)(t-1) * B_ + r) * H_ : zp + (size_t)r * H_) + ch * 64;
                _Float16* d1 = stA + r * ROWP + ch * 64;
                #pragma unroll
                for (int u = 0; u < 8; ++u) *(uint4*)(d1 + u*8) = *(const uint4*)(s1 + u*8);
            } else {
                const _Float16* s1 = h1 + ((size_t)t * B_ + r) * H_ + ch * 64;
                const _Float16* s2 = (t ? h2 + ((size_t)(t-1) * B_ + r) * H_ : zp + (size_t)r * H_) + ch * 64;
                _Float16* d1 = stA + r * ROWP + ch * 64;
                _Float16* d2 = stB + r * ROWP + ch * 64;
                #pragma unroll
                for (int u = 0; u < 8; ++u) *(uint4*)(d1 + u*8) = *(const uint4*)(s1 + u*8);
                #pragma unroll
                for (int u = 0; u < 8; ++u) *(uint4*)(d2 + u*8) = *(const uint4*)(s2 + u*8);
            }
        }
        // dom0: fetch xz slice (ring reuses addresses -> agent-scope dword loads)
        float xzv[4] = {0.f, 0.f, 0.f, 0.f};
        if (dom == 0) {
            const size_t base = (((size_t)((t >> 3) & 3) * 8 + (t & 7)) * B_ + bb) * G4_;
            #pragma unroll
            for (int g = 0; g < 4; ++g) {
                const unsigned* dp = (const unsigned*)&xzr[base + g * 1024 + (jcol & ~1)];
                unsigned dv = ldA(dp);
                unsigned short hb = (jcol & 1) ? (unsigned short)(dv >> 16) : (unsigned short)(dv & 0xffff);
                _Float16 hf; __builtin_memcpy(&hf, &hb, 2);
                xzv[g] = (float)hf;
            }
        }
        __syncthreads();   // S2: stage visible

        // ---- MFMA from LDS x reg-weights ----
        if (dom == 0) {
            const int mt = w >> 2, g = w & 3;
            const _Float16* ar = stA + (mt * 16 + (l & 15)) * ROWP;
            f32x4 aE = {0,0,0,0}, aO = {0,0,0,0};
            #pragma unroll
            for (int kiG = 0; kiG < 32; kiG += 2) {
                f16x8 a0 = *(const f16x8*)&ar[kiG * 32 + koff];
                f16x8 a1 = *(const f16x8*)&ar[(kiG + 1) * 32 + koff];
                aE = __builtin_amdgcn_mfma_f32_16x16x32_f16(a0, wf[kiG],   aE, 0, 0, 0);
                aO = __builtin_amdgcn_mfma_f32_16x16x32_f16(a1, wf[kiG+1], aO, 0, 0, 0);
            }
            f32x4 acc = aE + aO;
            #pragma unroll
            for (int i = 0; i < 4; ++i)
                red0[((mt * 4 + g) * 16 + (l >> 4) * 4 + i) * 17 + (l & 15)] = acc[i];
        } else {
            const int rl = w >> 2, g = w & 3;
            const _Float16* ab = rl ? stB : stA;
            f32x4 ac0 = {0,0,0,0}, ac1 = {0,0,0,0};
            #pragma unroll
            for (int kiG = 0; kiG < 32; ++kiG) {
                const int kk = kiG * 32 + koff;
                f16x8 bfr = wf[kiG];
                f16x8 a0 = *(const f16x8*)&ab[( 0 + (l & 15)) * ROWP + kk];
                f16x8 a1 = *(const f16x8*)&ab[(16 + (l & 15)) * ROWP + kk];
                ac0 = __builtin_amdgcn_mfma_f32_16x16x32_f16(a0, bfr, ac0, 0, 0, 0);
                ac1 = __builtin_amdgcn_mfma_f32_16x16x32_f16(a1, bfr, ac1, 0, 0, 0);
            }
            #pragma unroll
            for (int i = 0; i < 4; ++i) {
                red1[(((rl * 2 + 0) * 4 + g) * 16 + (l >> 4) * 4 + i) * 17 + (l & 15)] = ac0[i];
                red1[(((rl * 2 + 1) * 4 + g) * 16 + (l >> 4) * 4 + i) * 17 + (l & 15)] = ac1[i];
            }
        }
        __syncthreads();   // S3: red ready

        // ---- combine + state update + publish (every thread owns one output) ----
        {
            float z[4];
            if (dom == 0) {
                #pragma unroll
                for (int g = 0; g < 4; ++g)
                    z[g] = red0[(((bb >> 4) * 4 + g) * 16 + (bb & 15)) * 17 + jj] + xzv[g] + bias_[g];
            } else {
                #pragma unroll
                for (int g = 0; g < 4; ++g)
                    z[g] = red1[(((0 * 2 + (bb >> 4)) * 4 + g) * 16 + (bb & 15)) * 17 + jj]
                         + red1[(((1 * 2 + (bb >> 4)) * 4 + g) * 16 + (bb & 15)) * 17 + jj] + bias_[g];
            }
            float ig = hardsig(z[0]), fg = hardsig(z[1]);
            float gg = fast_tanh(z[2]), og = hardsig(z[3]);
            creg = fg * creg + ig * gg;
            float hval = og * fast_tanh(creg);
            _Float16 hf = (_Float16)hval;
            unsigned short us; __builtin_memcpy(&us, &hf, 2);
            unsigned up = us;
            unsigned op = (unsigned)__shfl_xor((int)up, 1);
            if (!(tid & 1)) {
                unsigned val = up | (op << 16);
                _Float16* arr = dom ? h2 : h1;
                stA32((unsigned*)&arr[((size_t)t * B_ + bb) * H_ + jcol], val);
            }
            if (dom == 1 && t == T_ - 1) out[(size_t)bb * H_ + jcol] = hval;
        }
        asm volatile("s_waitcnt vmcnt(0)" ::: "memory");   // publishes ACKed at LLC
        __syncthreads();   // S4: whole block ACKed

        if (tid == 0) {
            unsigned* ap = dom ? &ctr[16] : &ctr[0];
            unsigned old = __hip_atomic_fetch_add(ap, 1u, __ATOMIC_RELAXED, __HIP_MEMORY_SCOPE_AGENT);
            if ((old & 63u) == 63u) {
                unsigned* gp = dom ? &ctr[320] : &ctr[64];
                #pragma unroll
                for (int i = 0; i < 16; ++i) stA32(gp + i * 16, (unsigned)(t + 1));
            }
        }
    }
}

extern "C" void kernel_launch(void* const* d_in, const int* in_sizes, int n_in,
                              void* d_out, int out_size, void* d_ws, size_t ws_size,
                              hipStream_t stream) {
    const float* x  = (const float*)d_in[0];
    const float* W0 = (const float*)d_in[1];
    const float* U0 = (const float*)d_in[2];
    const float* b0 = (const float*)d_in[3];
    const float* W1 = (const float*)d_in[4];
    const float* U1 = (const float*)d_in[5];
    const float* b1 = (const float*)d_in[6];
    float* out = (float*)d_out;

    char* ws = (char*)d_ws;
    const size_t off_h1 = 0;          // 32 MiB  h1 fp16 [T][B][H]
    const size_t off_h2 = 33554432;   // 32 MiB  h2 fp16 [T][B][H]
    const size_t off_xz = 67108864;   //  8 MiB  xz ring fp16 [4][8][B][4H]
    const size_t off_zp = 75497472;   // 64 KiB  fp16 zeros
    const size_t off_ct = 75563008;   //  4 KiB  counters

    _Float16* h1  = (_Float16*)(ws + off_h1);
    _Float16* h2  = (_Float16*)(ws + off_h2);
    _Float16* xzr = (_Float16*)(ws + off_xz);
    _Float16* zp  = (_Float16*)(ws + off_zp);
    unsigned* ctr = (unsigned*)(ws + off_ct);

    // reset zero page + counters every launch (graph-capture safe)
    hipMemsetAsync(ws + off_zp, 0, 65536 + 4096, stream);

    hipLaunchKernelGGL(lstm3, dim3(256), dim3(NT), 0, stream,
                       x, W0, U0, b0, W1, U1, b1,
                       h1, h2, xzr, zp, ctr, out);
}